// Round 11
// baseline (167.407 us; speedup 1.0000x reference)
//
#include <hip/hip_runtime.h>
#include <cmath>

typedef unsigned short u16;
typedef unsigned int u32;
typedef __bf16 bf16x2 __attribute__((ext_vector_type(2)));
typedef __bf16 bf16x8 __attribute__((ext_vector_type(8)));
typedef float f32x16 __attribute__((ext_vector_type(16)));

#define NQ (768*768)
#define NK (384*768)

// ---------- helpers ----------
__device__ __forceinline__ u16 f2bf(float f) {
  u32 u = __float_as_uint(f);
  u32 r = (u + 0x7FFFu + ((u >> 16) & 1u)) >> 16;  // RNE
  return (u16)r;
}
__device__ __forceinline__ u32 packbf(float a, float b) {
#if __has_builtin(__builtin_amdgcn_cvt_pk_bf16_f32)
  bf16x2 v = __builtin_amdgcn_cvt_pk_bf16_f32(a, b);
  u32 r; __builtin_memcpy(&r, &v, 4); return r;
#else
  return (u32)f2bf(a) | ((u32)f2bf(b) << 16);
#endif
}
__device__ __forceinline__ float fexp2(float x) {
#if __has_builtin(__builtin_amdgcn_exp2f)
  return __builtin_amdgcn_exp2f(x);
#else
  return exp2f(x);
#endif
}
__device__ __forceinline__ bf16x8 ldfrag(const u16* p) { bf16x8 v; __builtin_memcpy(&v, p, 16); return v; }
__device__ __forceinline__ f32x16 mfma32_(bf16x8 a, bf16x8 b, f32x16 c) {
  return __builtin_amdgcn_mfma_f32_32x32x16_bf16(a, b, c, 0, 0, 0);
}

// Fragment-tiled layouts (ALL GEMM/attn operand loads are base + lane*16B, coalesced):
// actF / wF (K=768): [r>>5][k>>4][ lane=(r&31)+32*((k>>3)&1) ][ k&7 ]  (24576 els per 32-row group)
// K':  per (b,kvh): [s>>5][d>>4][ lane=(s&31)+32*((d>>3)&1) ][ d&7 ]
// V':  per (b,kvh): [p>>6][d>>5][ (p>>4)&3 ][ lane=(d&31)+32*((p>>3)&1) ][ p&7 ]  (p = sigma(s), bits 2<->3)
// Q':  [b][s>>5][h][d>>4][ lane=(s&31)+32*((d>>3)&1) ][ d&7 ]
__device__ __forceinline__ int fidx(int r, int k) {
  return (r >> 5) * 24576 + (k >> 4) * 512 + ((r & 31) + 32 * ((k >> 3) & 1)) * 8 + (k & 7);
}
__device__ __forceinline__ int kidx(int b6kvh, int s, int d) {
  return b6kvh * 131072 + (s >> 5) * 2048 + (d >> 4) * 512 +
         ((s & 31) + 32 * ((d >> 3) & 1)) * 8 + (d & 7);
}
__device__ __forceinline__ int qidx(int b, int s, int h, int d) {
  return ((b * 64 + (s >> 5)) * 12 + h) * 2048 + (d >> 4) * 512 +
         ((s & 31) + 32 * ((d >> 3) & 1)) * 8 + (d & 7);
}
__device__ __forceinline__ int vidx(int b6kvh, int d, int p) {
  return b6kvh * 131072 + (p >> 6) * 4096 + (d >> 5) * 2048 + ((p >> 4) & 3) * 512 +
         ((d & 31) + 32 * ((p >> 3) & 1)) * 8 + (p & 7);
}

// ---------- 1) sum(|w|) per matrix -> per-block partials (no atomics, no memset) ----------
__global__ __launch_bounds__(256) void abssum_kernel(const float* __restrict__ wq, const float* __restrict__ wk,
                                                     const float* __restrict__ wv, const float* __restrict__ wo,
                                                     float* __restrict__ part) {
  int which = blockIdx.y;
  const float* w = (which == 0) ? wq : (which == 1) ? wk : (which == 2) ? wv : wo;
  int n4 = ((which == 0 || which == 3) ? NQ : NK) >> 2;
  const float4* w4 = (const float4*)w;
  float s = 0.f;
  for (int i = blockIdx.x * blockDim.x + threadIdx.x; i < n4; i += gridDim.x * blockDim.x) {
    float4 v = w4[i];
    s += fabsf(v.x) + fabsf(v.y) + fabsf(v.z) + fabsf(v.w);
  }
  for (int off = 32; off; off >>= 1) s += __shfl_down(s, off);
  __shared__ float ls[4];
  if ((threadIdx.x & 63) == 0) ls[threadIdx.x >> 6] = s;
  __syncthreads();
  if (threadIdx.x == 0) part[which * 64 + blockIdx.x] = ls[0] + ls[1] + ls[2] + ls[3];
}

// ---------- 2) prep: reduce partials in-block, ternary-quantize weights + cast x ----------
__global__ __launch_bounds__(256) void prep_kernel(const float* __restrict__ wq, const float* __restrict__ wk,
                                                   const float* __restrict__ wv, const float* __restrict__ wo,
                                                   const float* __restrict__ part, const float* __restrict__ x,
                                                   u16* __restrict__ qw, u16* __restrict__ woq,
                                                   u16* __restrict__ xb) {
  __shared__ float ssum[4];
  {
    int t = threadIdx.x, wv64 = t >> 6, ln = t & 63;
    float p = part[t];                       // wave wv64 reduces matrix wv64's 64 partials
    for (int off = 32; off; off >>= 1) p += __shfl_down(p, off);
    if (ln == 0) ssum[wv64] = p;
  }
  __syncthreads();
  int i = blockIdx.x * blockDim.x + threadIdx.x;
  if (i < 221184) {
    int n = i / 96, k8 = i - n * 96;
    const float* src; float th; u16* dst; int nd;
    if (n < 768)       { src = wq + n * 768;          th = 0.7f * ssum[0] * (1.f / NQ); dst = qw;  nd = n; }
    else if (n < 1152) { src = wk + (n - 768) * 768;  th = 0.7f * ssum[1] * (1.f / NK); dst = qw;  nd = n; }
    else if (n < 1536) { src = wv + (n - 1152) * 768; th = 0.7f * ssum[2] * (1.f / NK); dst = qw;  nd = n; }
    else               { src = wo + (n - 1536) * 768; th = 0.7f * ssum[3] * (1.f / NQ); dst = woq; nd = n - 1536; }
    const float4* sp = (const float4*)(src + k8 * 8);
    float4 v0 = sp[0], v1 = sp[1];
    float e[8] = {v0.x, v0.y, v0.z, v0.w, v1.x, v1.y, v1.z, v1.w};
    u16 o[8];
#pragma unroll
    for (int j = 0; j < 8; j++)
      o[j] = f2bf((fabsf(e[j]) >= th) ? ((e[j] > 0.f) ? 1.f : -1.f) : 0.f);
    __builtin_memcpy(dst + fidx(nd, k8 * 8), o, 16);
  } else {
    int j = i - 221184;
    int m = j / 96, k8 = j - m * 96;
    const float4* xp = (const float4*)(x + m * 768 + k8 * 8);
    float4 v0 = xp[0], v1 = xp[1];
    u16 o[8] = { f2bf(v0.x), f2bf(v0.y), f2bf(v0.z), f2bf(v0.w),
                 f2bf(v1.x), f2bf(v1.y), f2bf(v1.z), f2bf(v1.w) };
    __builtin_memcpy(xb + fidx(m, k8 * 8), o, 16);
  }
}

// ---------- 3) fused QKV GEMM (barrier-free, 128m x 64n, 3 loads : 2 MFMA) + RoPE ----------
__global__ __launch_bounds__(256, 3) void gemm_qkv_kernel(const u16* __restrict__ xb, const u16* __restrict__ qw,
                                                          const float* __restrict__ part,
                                                          u16* __restrict__ qb, u16* __restrict__ kb,
                                                          u16* __restrict__ vT) {
  __shared__ float ssum[4];
  {
    int t = threadIdx.x, wv64 = t >> 6, ln = t & 63;
    float p = part[t];
    for (int off = 32; off; off >>= 1) p += __shfl_down(p, off);
    if (ln == 0) ssum[wv64] = p;
  }
  int tn = blockIdx.x, tm = blockIdx.y;
  int t = threadIdx.x, lane = t & 63, w = t >> 6, c = lane & 31, g2 = lane >> 5;
  const u16* abase = xb + (tm * 4 + w) * 24576 + lane * 8;
  const u16* bbase0 = qw + (tn * 2) * 24576 + lane * 8;
  const u16* bbase1 = bbase0 + 24576;
  f32x16 acc[2]; acc[0] = (f32x16)0.f; acc[1] = (f32x16)0.f;
  for (int kk = 0; kk < 48; kk += 4) {
#pragma unroll
    for (int ks = 0; ks < 4; ks++) {
      bf16x8 af = ldfrag(abase + (kk + ks) * 512);
      bf16x8 b0 = ldfrag(bbase0 + (kk + ks) * 512);
      bf16x8 b1 = ldfrag(bbase1 + (kk + ks) * 512);
      acc[0] = mfma32_(af, b0, acc[0]);
      acc[1] = mfma32_(af, b1, acc[1]);
    }
  }
  __syncthreads();
  float sq = ssum[0] * (1.f / NQ) * 0.180336880111120f;  // * 0.125 * log2(e)
  float sk = ssum[1] * (1.f / NK);
  float sv = ssum[2] * (1.f / NK);
  int mb = tm * 128 + w * 32 + 4 * g2;
  if (tn < 18) {
    float sc = (tn < 12) ? sq : sk;
    int head = (tn < 12) ? tn : (tn - 12);
    float f = fexp2((float)c * -0.41524101186092029f);   // 10000^(-c/32)
#pragma unroll
    for (int r = 0; r < 16; r++) {
      int m = mb + (r & 3) + 8 * (r >> 2);
      int bb = m >> 11, s = m & 2047;
      float sn, cs; sincosf((float)s * f, &sn, &cs);
      float x1 = acc[0][r] * sc, x2 = acc[1][r] * sc;
      u16 y1 = f2bf(x1 * cs - x2 * sn);       // dim d = c
      u16 y2 = f2bf(x2 * cs + x1 * sn);       // dim d = c + 32
      if (tn < 12) {
        qb[qidx(bb, s, head, c)]      = y1;
        qb[qidx(bb, s, head, c + 32)] = y2;
      } else {
        kb[kidx(bb * 6 + head, s, c)]      = y1;
        kb[kidx(bb * 6 + head, s, c + 32)] = y2;
      }
    }
  } else {
    int kvh = tn - 18;
#pragma unroll
    for (int nb = 0; nb < 2; nb++)
#pragma unroll
      for (int r = 0; r < 16; r++) {
        int m = mb + (r & 3) + 8 * (r >> 2);
        int bb = m >> 11, s = m & 2047;
        int sp = (s & ~12) | ((s & 4) << 1) | ((s & 8) >> 1);   // sigma: swap bits 2,3
        vT[vidx(bb * 6 + kvh, nb * 32 + c, sp)] = f2bf(acc[nb][r] * sv);
      }
  }
}

// ---------- 4) attention: 32 q/block, one head per wave, split-S ILP, unroll-2 key loop ----------
// grid (12 bk, 64 qt): bk fastest -> XCD L2 locality. 768 blocks = 3/CU at (256,3).
// waves: head hn = w&1, key-half kh = w>>1 (32 iters of 32 keys each).
__global__ __launch_bounds__(256, 3) void attn_kernel(const u16* __restrict__ qb, const u16* __restrict__ kb,
                                                      const u16* __restrict__ vT, u16* __restrict__ ab) {
  __shared__ float Obuf[4][32][66];
  __shared__ float Lbuf[4][32];
  int bk = blockIdx.x, qt = blockIdx.y;
  int b = bk / 6, kvh = bk % 6;
  int t = threadIdx.x, lane = t & 63, w = t >> 6, c = lane & 31, g2 = lane >> 5;
  int hn = w & 1, kh = w >> 1;

  const u16* qbase = qb + ((b * 64 + qt) * 12 + kvh * 2 + hn) * 2048;
  bf16x8 qf[4];
#pragma unroll
  for (int ks = 0; ks < 4; ks++) qf[ks] = ldfrag(qbase + ks * 512 + lane * 8);

  f32x16 fz = (f32x16)0.f;
  f32x16 O[2] = {fz, fz};
  float esum[16];
#pragma unroll
  for (int r = 0; r < 16; r++) esum[r] = 0.f;

  const u16* Kb = kb + bk * 131072;
  const u16* Vb = vT + bk * 131072;

#pragma unroll 2
  for (int it = 0; it < 32; it++) {
    int kb32 = kh * 32 + it;
    const u16* kt = Kb + kb32 * 2048;
    const u16* vt = Vb + (kb32 >> 1) * 4096 + (kb32 & 1) * 1024;
    bf16x8 kf[4];
#pragma unroll
    for (int ks = 0; ks < 4; ks++) kf[ks] = ldfrag(kt + ks * 512 + lane * 8);
    bf16x8 vf[2][2];
#pragma unroll
    for (int dn = 0; dn < 2; dn++)
#pragma unroll
      for (int ksv = 0; ksv < 2; ksv++)
        vf[dn][ksv] = ldfrag(vt + dn * 2048 + ksv * 512 + lane * 8);
    // two independent 2-MFMA chains instead of one 4-MFMA chain
    f32x16 S0 = fz, S1 = fz;
    S0 = mfma32_(kf[0], qf[0], S0);
    S1 = mfma32_(kf[1], qf[1], S1);
    S0 = mfma32_(kf[2], qf[2], S0);
    S1 = mfma32_(kf[3], qf[3], S1);
    float e[16];
#pragma unroll
    for (int r = 0; r < 16; r++) {
      e[r] = fexp2(S0[r] + S1[r]);
      esum[r] += e[r];
    }
    u32 P[8];
#pragma unroll
    for (int j = 0; j < 8; j++) P[j] = packbf(e[2 * j], e[2 * j + 1]);
    bf16x8 PA[2];
    __builtin_memcpy(&PA[0], &P[0], 16);
    __builtin_memcpy(&PA[1], &P[4], 16);
#pragma unroll
    for (int ksv = 0; ksv < 2; ksv++) {
      O[0] = mfma32_(PA[ksv], vf[0][ksv], O[0]);
      O[1] = mfma32_(PA[ksv], vf[1][ksv], O[1]);
    }
  }
  // row-sums: esum[r] holds (q-row, key lane c) partials; reduce across the 32 key lanes.
#pragma unroll
  for (int r = 0; r < 16; r++) {
    float v = esum[r];
    v += __shfl_xor(v, 1); v += __shfl_xor(v, 2); v += __shfl_xor(v, 4);
    v += __shfl_xor(v, 8); v += __shfl_xor(v, 16);
    esum[r] = v;
  }
  if (c == 0) {
#pragma unroll
    for (int r = 0; r < 16; r++) Lbuf[w][(r & 3) + 8 * (r >> 2) + 4 * g2] = esum[r];
  }
#pragma unroll
  for (int dn = 0; dn < 2; dn++)
#pragma unroll
    for (int r = 0; r < 16; r++)
      Obuf[w][(r & 3) + 8 * (r >> 2) + 4 * g2][dn * 32 + c] = O[dn][r];
  __syncthreads();
  {
    int hn_c = t >> 7, qq = (t >> 2) & 31, dc = (t & 3) * 16;
    float l = Lbuf[hn_c][qq] + Lbuf[hn_c + 2][qq];
    float inv = 1.f / l;
    u16 o[16];
#pragma unroll
    for (int j = 0; j < 16; j++)
      o[j] = f2bf((Obuf[hn_c][qq][dc + j] + Obuf[hn_c + 2][qq][dc + j]) * inv);
    int h = kvh * 2 + hn_c;
    int mg = b * 64 + qt;
    u16* dst = ab + mg * 24576 + ((h * 64 + dc) >> 4) * 512 + qq * 8;
    __builtin_memcpy(dst, o, 16);            // d8-group 0
    __builtin_memcpy(dst + 256, o + 8, 16);  // d8-group 1
  }
}

// ---------- 5) output projection GEMM (barrier-free, 128m x 64n) -> fp32 ----------
__global__ __launch_bounds__(256, 3) void gemm_out_kernel(const u16* __restrict__ ab, const u16* __restrict__ woq,
                                                          const float* __restrict__ part, float* __restrict__ out) {
  __shared__ float ssum4;
  {
    int t = threadIdx.x;
    if (t < 64) {
      float p = part[192 + t];               // matrix 3 partials
      for (int off = 32; off; off >>= 1) p += __shfl_down(p, off);
      if (t == 0) ssum4 = p;
    }
  }
  int tn = blockIdx.x, tm = blockIdx.y;
  int t = threadIdx.x, lane = t & 63, w = t >> 6, c = lane & 31, g2 = lane >> 5;
  const u16* abase = ab + (tm * 4 + w) * 24576 + lane * 8;
  const u16* bbase0 = woq + (tn * 2) * 24576 + lane * 8;
  const u16* bbase1 = bbase0 + 24576;
  f32x16 acc[2]; acc[0] = (f32x16)0.f; acc[1] = (f32x16)0.f;
  for (int kk = 0; kk < 48; kk += 4) {
#pragma unroll
    for (int ks = 0; ks < 4; ks++) {
      bf16x8 af = ldfrag(abase + (kk + ks) * 512);
      bf16x8 b0 = ldfrag(bbase0 + (kk + ks) * 512);
      bf16x8 b1 = ldfrag(bbase1 + (kk + ks) * 512);
      acc[0] = mfma32_(af, b0, acc[0]);
      acc[1] = mfma32_(af, b1, acc[1]);
    }
  }
  __syncthreads();
  float so = ssum4 * (1.f / NQ);
  int mb = tm * 128 + w * 32 + 4 * g2;
#pragma unroll
  for (int nb = 0; nb < 2; nb++)
#pragma unroll
    for (int r = 0; r < 16; r++) {
      int m = mb + (r & 3) + 8 * (r >> 2);
      out[m * 768 + tn * 64 + nb * 32 + c] = acc[nb][r] * so;
    }
}

// ---------- launch ----------
extern "C" void kernel_launch(void* const* d_in, const int* in_sizes, int n_in,
                              void* d_out, int out_size, void* d_ws, size_t ws_size,
                              hipStream_t stream) {
  const float* x  = (const float*)d_in[0];
  const float* wq = (const float*)d_in[1];
  const float* wk = (const float*)d_in[2];
  const float* wv = (const float*)d_in[3];
  const float* wo = (const float*)d_in[4];
  float* out = (float*)d_out;
  char* ws = (char*)d_ws;

  u16* qw  = (u16*)(ws + 256);                 // ternary QKV weights, fragment-tiled (1536 rows)
  u16* woq = (u16*)(ws + 2359552);             // ternary O weights, fragment-tiled (768 rows)
  u16* xb  = (u16*)(ws + 3539200);             // x fragment-tiled
  u16* qb  = (u16*)(ws + 9830656);             // Q' fragment-tiled
  u16* kb  = (u16*)(ws + 16122112);            // K' fragment-tiled
  u16* vT  = (u16*)(ws + 19267840);            // V' fragment-tiled, key-permuted
  u16* ab  = (u16*)(ws + 22413568);            // attn out fragment-tiled
  float* part = (float*)(ws + 28705024);       // [4][64] abssum partials (1 KB)

  dim3 blk(256);
  abssum_kernel<<<dim3(64, 4), blk, 0, stream>>>(wq, wk, wv, wo, part);
  prep_kernel<<<dim3(2400), blk, 0, stream>>>(wq, wk, wv, wo, part, x, qw, woq, xb);
  gemm_qkv_kernel<<<dim3(24, 32), blk, 0, stream>>>(xb, qw, part, qb, kb, vT);
  attn_kernel<<<dim3(12, 64), blk, 0, stream>>>(qb, kb, vT, ab);
  gemm_out_kernel<<<dim3(12, 32), blk, 0, stream>>>(ab, woq, part, out);
}

// Round 12
// 157.699 us; speedup vs baseline: 1.0616x; 1.0616x over previous
//
#include <hip/hip_runtime.h>
#include <cmath>

typedef unsigned short u16;
typedef unsigned int u32;
typedef __bf16 bf16x2 __attribute__((ext_vector_type(2)));
typedef __bf16 bf16x8 __attribute__((ext_vector_type(8)));
typedef float f32x16 __attribute__((ext_vector_type(16)));

#define NQ (768*768)
#define NK (384*768)

// ---------- helpers ----------
__device__ __forceinline__ u16 f2bf(float f) {
  u32 u = __float_as_uint(f);
  u32 r = (u + 0x7FFFu + ((u >> 16) & 1u)) >> 16;  // RNE
  return (u16)r;
}
__device__ __forceinline__ u32 packbf(float a, float b) {
#if __has_builtin(__builtin_amdgcn_cvt_pk_bf16_f32)
  bf16x2 v = __builtin_amdgcn_cvt_pk_bf16_f32(a, b);
  u32 r; __builtin_memcpy(&r, &v, 4); return r;
#else
  return (u32)f2bf(a) | ((u32)f2bf(b) << 16);
#endif
}
__device__ __forceinline__ float fexp2(float x) {
#if __has_builtin(__builtin_amdgcn_exp2f)
  return __builtin_amdgcn_exp2f(x);
#else
  return exp2f(x);
#endif
}
__device__ __forceinline__ bf16x8 ldfrag(const u16* p) { bf16x8 v; __builtin_memcpy(&v, p, 16); return v; }
__device__ __forceinline__ f32x16 mfma32_(bf16x8 a, bf16x8 b, f32x16 c) {
  return __builtin_amdgcn_mfma_f32_32x32x16_bf16(a, b, c, 0, 0, 0);
}

// Fragment-tiled layouts (ALL GEMM/attn operand loads are base + lane*16B, coalesced):
// actF / wF (K=768): [r>>5][k>>4][ lane=(r&31)+32*((k>>3)&1) ][ k&7 ]  (24576 els per 32-row group)
// K':  per (b,kvh): [s>>5][d>>4][ lane=(s&31)+32*((d>>3)&1) ][ d&7 ]
// V':  per (b,kvh): [p>>6][d>>5][ (p>>4)&3 ][ lane=(d&31)+32*((p>>3)&1) ][ p&7 ]  (p = sigma(s), bits 2<->3)
// Q':  [b][s>>5][h][d>>4][ lane=(s&31)+32*((d>>3)&1) ][ d&7 ]
__device__ __forceinline__ int fidx(int r, int k) {
  return (r >> 5) * 24576 + (k >> 4) * 512 + ((r & 31) + 32 * ((k >> 3) & 1)) * 8 + (k & 7);
}
__device__ __forceinline__ int kidx(int b6kvh, int s, int d) {
  return b6kvh * 131072 + (s >> 5) * 2048 + (d >> 4) * 512 +
         ((s & 31) + 32 * ((d >> 3) & 1)) * 8 + (d & 7);
}
__device__ __forceinline__ int qidx(int b, int s, int h, int d) {
  return ((b * 64 + (s >> 5)) * 12 + h) * 2048 + (d >> 4) * 512 +
         ((s & 31) + 32 * ((d >> 3) & 1)) * 8 + (d & 7);
}
__device__ __forceinline__ int vidx(int b6kvh, int d, int p) {
  return b6kvh * 131072 + (p >> 6) * 4096 + (d >> 5) * 2048 + ((p >> 4) & 3) * 512 +
         ((d & 31) + 32 * ((p >> 3) & 1)) * 8 + (p & 7);
}

// ---------- 1) sum(|w|) per matrix -> per-block partials (no atomics, no memset) ----------
__global__ __launch_bounds__(256) void abssum_kernel(const float* __restrict__ wq, const float* __restrict__ wk,
                                                     const float* __restrict__ wv, const float* __restrict__ wo,
                                                     float* __restrict__ part) {
  int which = blockIdx.y;
  const float* w = (which == 0) ? wq : (which == 1) ? wk : (which == 2) ? wv : wo;
  int n4 = ((which == 0 || which == 3) ? NQ : NK) >> 2;
  const float4* w4 = (const float4*)w;
  float s = 0.f;
  for (int i = blockIdx.x * blockDim.x + threadIdx.x; i < n4; i += gridDim.x * blockDim.x) {
    float4 v = w4[i];
    s += fabsf(v.x) + fabsf(v.y) + fabsf(v.z) + fabsf(v.w);
  }
  for (int off = 32; off; off >>= 1) s += __shfl_down(s, off);
  __shared__ float ls[4];
  if ((threadIdx.x & 63) == 0) ls[threadIdx.x >> 6] = s;
  __syncthreads();
  if (threadIdx.x == 0) part[which * 64 + blockIdx.x] = ls[0] + ls[1] + ls[2] + ls[3];
}

// ---------- 2) prep: reduce partials in-block, ternary-quantize weights + cast x ----------
__global__ __launch_bounds__(256) void prep_kernel(const float* __restrict__ wq, const float* __restrict__ wk,
                                                   const float* __restrict__ wv, const float* __restrict__ wo,
                                                   const float* __restrict__ part, const float* __restrict__ x,
                                                   u16* __restrict__ qw, u16* __restrict__ woq,
                                                   u16* __restrict__ xb) {
  __shared__ float ssum[4];
  {
    int t = threadIdx.x, wv64 = t >> 6, ln = t & 63;
    float p = part[t];                       // wave wv64 reduces matrix wv64's 64 partials
    for (int off = 32; off; off >>= 1) p += __shfl_down(p, off);
    if (ln == 0) ssum[wv64] = p;
  }
  __syncthreads();
  int i = blockIdx.x * blockDim.x + threadIdx.x;
  if (i < 221184) {
    int n = i / 96, k8 = i - n * 96;
    const float* src; float th; u16* dst; int nd;
    if (n < 768)       { src = wq + n * 768;          th = 0.7f * ssum[0] * (1.f / NQ); dst = qw;  nd = n; }
    else if (n < 1152) { src = wk + (n - 768) * 768;  th = 0.7f * ssum[1] * (1.f / NK); dst = qw;  nd = n; }
    else if (n < 1536) { src = wv + (n - 1152) * 768; th = 0.7f * ssum[2] * (1.f / NK); dst = qw;  nd = n; }
    else               { src = wo + (n - 1536) * 768; th = 0.7f * ssum[3] * (1.f / NQ); dst = woq; nd = n - 1536; }
    const float4* sp = (const float4*)(src + k8 * 8);
    float4 v0 = sp[0], v1 = sp[1];
    float e[8] = {v0.x, v0.y, v0.z, v0.w, v1.x, v1.y, v1.z, v1.w};
    u16 o[8];
#pragma unroll
    for (int j = 0; j < 8; j++)
      o[j] = f2bf((fabsf(e[j]) >= th) ? ((e[j] > 0.f) ? 1.f : -1.f) : 0.f);
    __builtin_memcpy(dst + fidx(nd, k8 * 8), o, 16);
  } else {
    int j = i - 221184;
    int m = j / 96, k8 = j - m * 96;
    const float4* xp = (const float4*)(x + m * 768 + k8 * 8);
    float4 v0 = xp[0], v1 = xp[1];
    u16 o[8] = { f2bf(v0.x), f2bf(v0.y), f2bf(v0.z), f2bf(v0.w),
                 f2bf(v1.x), f2bf(v1.y), f2bf(v1.z), f2bf(v1.w) };
    __builtin_memcpy(xb + fidx(m, k8 * 8), o, 16);
  }
}

// ---------- 3) fused QKV GEMM (barrier-free, 64m x 128n) + scale + RoPE + tiled outputs ----------
// grid (12 tn, 64 tm). 4 waves: wm = w&1 (m-half), wn = w>>1 (n-half = one head's 64 cols).
// tn<6: Q head=2tn+wn. tn<9: K kvh=2(tn-6)+wn. else V kvh=2(tn-9)+wn.
__global__ __launch_bounds__(256, 3) void gemm_qkv_kernel(const u16* __restrict__ xb, const u16* __restrict__ qw,
                                                          const float* __restrict__ part,
                                                          u16* __restrict__ qb, u16* __restrict__ kb,
                                                          u16* __restrict__ vT) {
  __shared__ float ssum[4];
  {
    int t = threadIdx.x, wv64 = t >> 6, ln = t & 63;
    float p = part[t];
    for (int off = 32; off; off >>= 1) p += __shfl_down(p, off);
    if (ln == 0) ssum[wv64] = p;
  }
  int tn = blockIdx.x, tm = blockIdx.y;
  int t = threadIdx.x, lane = t & 63, w = t >> 6, c = lane & 31, g2 = lane >> 5;
  int wm = w & 1, wn = w >> 1;
  const u16* abase = xb + (tm * 2 + wm) * 24576 + lane * 8;
  const u16* bbase0 = qw + (tn * 4 + wn * 2) * 24576 + lane * 8;
  const u16* bbase1 = bbase0 + 24576;
  f32x16 acc[2]; acc[0] = (f32x16)0.f; acc[1] = (f32x16)0.f;
  for (int kk = 0; kk < 48; kk += 4) {
#pragma unroll
    for (int ks = 0; ks < 4; ks++) {
      bf16x8 af = ldfrag(abase + (kk + ks) * 512);
      bf16x8 b0 = ldfrag(bbase0 + (kk + ks) * 512);
      bf16x8 b1 = ldfrag(bbase1 + (kk + ks) * 512);
      acc[0] = mfma32_(af, b0, acc[0]);
      acc[1] = mfma32_(af, b1, acc[1]);
    }
  }
  __syncthreads();   // orders ssum writes before epilogue reads
  float sq = ssum[0] * (1.f / NQ) * 0.180336880111120f;  // * 0.125 * log2(e)
  float sk = ssum[1] * (1.f / NK);
  float sv = ssum[2] * (1.f / NK);
  int mb = tm * 64 + wm * 32 + 4 * g2;
  if (tn < 9) {
    float sc = (tn < 6) ? sq : sk;
    int head = (tn < 6) ? (tn * 2 + wn) : ((tn - 6) * 2 + wn);
    float f = fexp2((float)c * -0.41524101186092029f);   // 10000^(-c/32)
#pragma unroll
    for (int r = 0; r < 16; r++) {
      int m = mb + (r & 3) + 8 * (r >> 2);
      int bb = m >> 11, s = m & 2047;
      float sn, cs; sincosf((float)s * f, &sn, &cs);
      float x1 = acc[0][r] * sc, x2 = acc[1][r] * sc;
      u16 y1 = f2bf(x1 * cs - x2 * sn);       // dim d = c
      u16 y2 = f2bf(x2 * cs + x1 * sn);       // dim d = c + 32
      if (tn < 6) {
        qb[qidx(bb, s, head, c)]      = y1;
        qb[qidx(bb, s, head, c + 32)] = y2;
      } else {
        kb[kidx(bb * 6 + head, s, c)]      = y1;
        kb[kidx(bb * 6 + head, s, c + 32)] = y2;
      }
    }
  } else {
    int kvh = (tn - 9) * 2 + wn;
#pragma unroll
    for (int nb = 0; nb < 2; nb++)
#pragma unroll
      for (int r = 0; r < 16; r++) {
        int m = mb + (r & 3) + 8 * (r >> 2);
        int bb = m >> 11, s = m & 2047;
        int sp = (s & ~12) | ((s & 4) << 1) | ((s & 8) >> 1);   // sigma: swap bits 2,3
        vT[vidx(bb * 6 + kvh, nb * 32 + c, sp)] = f2bf(acc[nb][r] * sv);
      }
  }
}

// ---------- 4) attention: one head per wave, 32 keys/iter, lsum via ones-MFMA ----------
// grid (12 bk, 64 qt): bk fastest -> XCD L2 locality. 768 blocks = 3/CU at (256,3).
// waves: head hn = w&1, key-half kh = w>>1 (32 iters of 32 keys each).
__global__ __launch_bounds__(256, 3) void attn_kernel(const u16* __restrict__ qb, const u16* __restrict__ kb,
                                                      const u16* __restrict__ vT, u16* __restrict__ ab) {
  __shared__ float Obuf[4][32][66];
  __shared__ float Lbuf[4][32];
  int bk = blockIdx.x, qt = blockIdx.y;
  int b = bk / 6, kvh = bk % 6;
  int t = threadIdx.x, lane = t & 63, w = t >> 6, c = lane & 31, g2 = lane >> 5;
  int hn = w & 1, kh = w >> 1;

  const u16* qbase = qb + ((b * 64 + qt) * 12 + kvh * 2 + hn) * 2048;
  bf16x8 qf[4];
#pragma unroll
  for (int ks = 0; ks < 4; ks++) qf[ks] = ldfrag(qbase + ks * 512 + lane * 8);

  u32 onesw = 0x3F803F80u;
  bf16x8 ones;
  { u32 tmp[4] = {onesw, onesw, onesw, onesw}; __builtin_memcpy(&ones, tmp, 16); }

  f32x16 fz = (f32x16)0.f;
  f32x16 O[2] = {fz, fz};
  f32x16 Lacc = fz;

  const u16* Kb = kb + bk * 131072;
  const u16* Vb = vT + bk * 131072;

  for (int it = 0; it < 32; it++) {
    int kb32 = kh * 32 + it;                       // 32-key group index
    const u16* kt = Kb + kb32 * 2048;
    const u16* vt = Vb + (kb32 >> 1) * 4096 + (kb32 & 1) * 1024;
    bf16x8 kf[4];
#pragma unroll
    for (int ks = 0; ks < 4; ks++) kf[ks] = ldfrag(kt + ks * 512 + lane * 8);
    bf16x8 vf[2][2];
#pragma unroll
    for (int dn = 0; dn < 2; dn++)
#pragma unroll
      for (int ksv = 0; ksv < 2; ksv++)
        vf[dn][ksv] = ldfrag(vt + dn * 2048 + ksv * 512 + lane * 8);
    f32x16 S = fz;
#pragma unroll
    for (int ks = 0; ks < 4; ks++) S = mfma32_(kf[ks], qf[ks], S);
    float e[16];
#pragma unroll
    for (int r = 0; r < 16; r++) e[r] = fexp2(S[r]);
    u32 P[8];
#pragma unroll
    for (int j = 0; j < 8; j++) P[j] = packbf(e[2 * j], e[2 * j + 1]);
    bf16x8 PA[2];
    __builtin_memcpy(&PA[0], &P[0], 16);
    __builtin_memcpy(&PA[1], &P[4], 16);
#pragma unroll
    for (int ksv = 0; ksv < 2; ksv++) {
      O[0] = mfma32_(PA[ksv], vf[0][ksv], O[0]);
      O[1] = mfma32_(PA[ksv], vf[1][ksv], O[1]);
      Lacc = mfma32_(PA[ksv], ones, Lacc);
    }
  }
  if (c == 0) {
#pragma unroll
    for (int r = 0; r < 16; r++) Lbuf[w][(r & 3) + 8 * (r >> 2) + 4 * g2] = Lacc[r];
  }
#pragma unroll
  for (int dn = 0; dn < 2; dn++)
#pragma unroll
    for (int r = 0; r < 16; r++)
      Obuf[w][(r & 3) + 8 * (r >> 2) + 4 * g2][dn * 32 + c] = O[dn][r];
  __syncthreads();
  {
    int hn_c = t >> 7, qq = (t >> 2) & 31, dc = (t & 3) * 16;
    float l = Lbuf[hn_c][qq] + Lbuf[hn_c + 2][qq];
    float inv = 1.f / l;
    u16 o[16];
#pragma unroll
    for (int j = 0; j < 16; j++)
      o[j] = f2bf((Obuf[hn_c][qq][dc + j] + Obuf[hn_c + 2][qq][dc + j]) * inv);
    int h = kvh * 2 + hn_c;
    int mg = b * 64 + qt;
    u16* dst = ab + mg * 24576 + ((h * 64 + dc) >> 4) * 512 + qq * 8;
    __builtin_memcpy(dst, o, 16);            // d8-group 0
    __builtin_memcpy(dst + 256, o + 8, 16);  // d8-group 1
  }
}

// ---------- 5) output projection GEMM (barrier-free, no LDS, 64m x 64n) -> fp32 ----------
__global__ __launch_bounds__(256, 3) void gemm_out_kernel(const u16* __restrict__ ab, const u16* __restrict__ woq,
                                                          const float* __restrict__ part, float* __restrict__ out) {
  __shared__ float ssum4;
  {
    int t = threadIdx.x;
    if (t < 64) {
      float p = part[192 + t];               // matrix 3 partials
      for (int off = 32; off; off >>= 1) p += __shfl_down(p, off);
      if (t == 0) ssum4 = p;
    }
  }
  int tn = blockIdx.x, tm = blockIdx.y;
  int t = threadIdx.x, lane = t & 63, w = t >> 6, c = lane & 31, g2 = lane >> 5;
  int wm = w & 1, wn = w >> 1;
  const u16* abase = ab + (tm * 2 + wm) * 24576 + lane * 8;
  const u16* bbase = woq + (tn * 2 + wn) * 24576 + lane * 8;
  f32x16 acc = (f32x16)0.f;
  for (int kk = 0; kk < 48; kk += 4) {
#pragma unroll
    for (int ks = 0; ks < 4; ks++) {
      bf16x8 af = ldfrag(abase + (kk + ks) * 512);
      bf16x8 bf = ldfrag(bbase + (kk + ks) * 512);
      acc = mfma32_(af, bf, acc);
    }
  }
  __syncthreads();   // orders ssum4 write before epilogue reads
  float so = ssum4 * (1.f / NQ);
  int mb = tm * 64 + wm * 32 + 4 * g2;
#pragma unroll
  for (int r = 0; r < 16; r++) {
    int m = mb + (r & 3) + 8 * (r >> 2);
    out[m * 768 + tn * 64 + wn * 32 + c] = acc[r] * so;
  }
}

// ---------- launch ----------
extern "C" void kernel_launch(void* const* d_in, const int* in_sizes, int n_in,
                              void* d_out, int out_size, void* d_ws, size_t ws_size,
                              hipStream_t stream) {
  const float* x  = (const float*)d_in[0];
  const float* wq = (const float*)d_in[1];
  const float* wk = (const float*)d_in[2];
  const float* wv = (const float*)d_in[3];
  const float* wo = (const float*)d_in[4];
  float* out = (float*)d_out;
  char* ws = (char*)d_ws;

  u16* qw  = (u16*)(ws + 256);                 // ternary QKV weights, fragment-tiled (1536 rows)
  u16* woq = (u16*)(ws + 2359552);             // ternary O weights, fragment-tiled (768 rows)
  u16* xb  = (u16*)(ws + 3539200);             // x fragment-tiled
  u16* qb  = (u16*)(ws + 9830656);             // Q' fragment-tiled
  u16* kb  = (u16*)(ws + 16122112);            // K' fragment-tiled
  u16* vT  = (u16*)(ws + 19267840);            // V' fragment-tiled, key-permuted
  u16* ab  = (u16*)(ws + 22413568);            // attn out fragment-tiled
  float* part = (float*)(ws + 28705024);       // [4][64] abssum partials (1 KB)

  dim3 blk(256);
  abssum_kernel<<<dim3(64, 4), blk, 0, stream>>>(wq, wk, wv, wo, part);
  prep_kernel<<<dim3(2400), blk, 0, stream>>>(wq, wk, wv, wo, part, x, qw, woq, xb);
  gemm_qkv_kernel<<<dim3(12, 64), blk, 0, stream>>>(xb, qw, part, qb, kb, vT);
  attn_kernel<<<dim3(12, 64), blk, 0, stream>>>(qb, kb, vT, ab);
  gemm_out_kernel<<<dim3(12, 64), blk, 0, stream>>>(ab, woq, part, out);
}